// Round 5
// baseline (321.659 us; speedup 1.0000x reference)
//
#include <hip/hip_runtime.h>
#include <math.h>

#define NN 50000
#define NE 800000
#define HD 64
#define NBK 196  // dst buckets (256 nodes each)
#define BSE 2048 // edges per block in bucket count/scatter
#define DT 5     // decoder tiles per wave (NE = 1250 blocks * 4 waves * 32 * DT)

typedef float f32x4 __attribute__((ext_vector_type(4)));
typedef float f32x16 __attribute__((ext_vector_type(16)));
typedef short short8 __attribute__((ext_vector_type(8)));
typedef _Float16 hf2 __attribute__((ext_vector_type(2)));
typedef _Float16 half8 __attribute__((ext_vector_type(8)));

__device__ __forceinline__ float wave_sum(float v) {
  #pragma unroll
  for (int off = 32; off > 0; off >>= 1) v += __shfl_xor(v, off, 64);
  return v;
}

// ---- fp16 conversion helpers ----
__device__ __forceinline__ unsigned f2h_pk(float a, float b) {
  auto v = __builtin_amdgcn_cvt_pkrtz(a, b);     // v_cvt_pkrtz_f16_f32
  union { decltype(v) h; unsigned u; } cv; cv.h = v; return cv.u;
}
__device__ __forceinline__ unsigned short f2h(float a) {
  union { _Float16 h; unsigned short u; } cv; cv.h = (_Float16)a; return cv.u;  // RNE
}
__device__ __forceinline__ float h2f(unsigned short b) {
  union { unsigned short u; _Float16 h; } v; v.u = b; return (float)v.h;
}

// =================== bucketed counting sort of edges by (dst, r) ===================
// K1: per-bucket edge counts (LDS histogram, 1 global atomic per bucket per block)
__global__ __launch_bounds__(256) void bucket_count(
    const int* __restrict__ ei, int* __restrict__ bcnt)
{
  __shared__ int h[NBK];
  for (int i = threadIdx.x; i < NBK; i += 256) h[i] = 0;
  __syncthreads();
  int e0 = blockIdx.x * BSE;
  #pragma unroll
  for (int k = 0; k < BSE / 256; k++) {
    int e = e0 + k * 256 + threadIdx.x;
    if (e < NE) atomicAdd(&h[ei[NE + e] >> 8], 1);
  }
  __syncthreads();
  for (int i = threadIdx.x; i < NBK; i += 256)
    if (h[i]) atomicAdd(&bcnt[i], h[i]);
}

// K2: exclusive scan of bucket counts -> bbase (197 entries), init bcur
__global__ __launch_bounds__(256) void bucket_scan(
    const int* __restrict__ bcnt, int* __restrict__ bbase, int* __restrict__ bcur)
{
  __shared__ int sd[256];
  int v = (threadIdx.x < NBK) ? bcnt[threadIdx.x] : 0;
  sd[threadIdx.x] = v;
  __syncthreads();
  for (int s = 1; s < 256; s <<= 1) {
    int t = (threadIdx.x >= s) ? sd[threadIdx.x - s] : 0;
    __syncthreads();
    sd[threadIdx.x] += t;
    __syncthreads();
  }
  if (threadIdx.x < NBK) {
    int ex = sd[threadIdx.x] - v;
    bbase[threadIdx.x] = ex;
    bcur[threadIdx.x] = ex;
  }
  if (threadIdx.x == 0) bbase[NBK] = NE;
}

// K3: scatter packed records (src | dlow<<16 | r<<24) into bucket-contiguous regions
__global__ __launch_bounds__(256) void bucket_scatter(
    const int* __restrict__ ei, const float* __restrict__ ea,
    int* __restrict__ bcur, unsigned* __restrict__ recs)
{
  __shared__ int hcnt[NBK], hbase[NBK];
  for (int i = threadIdx.x; i < NBK; i += 256) hcnt[i] = 0;
  __syncthreads();
  const float q1 = log1pf(5000.0f);
  const float q2 = log1pf(10000.0f);
  int e0 = blockIdx.x * BSE;
  unsigned rec[BSE / 256];
  int bk[BSE / 256];
  #pragma unroll
  for (int k = 0; k < BSE / 256; k++) {
    int e = e0 + k * 256 + threadIdx.x;
    bk[k] = -1;
    if (e < NE) {
      int s = ei[e], d = ei[NE + e];
      float dist = ea[(size_t)e * 6];
      int r = (dist > q1 ? 1 : 0) + (dist > q2 ? 1 : 0);
      rec[k] = (unsigned)s | ((unsigned)(d & 255) << 16) | ((unsigned)r << 24);
      bk[k] = d >> 8;
      atomicAdd(&hcnt[bk[k]], 1);
    }
  }
  __syncthreads();
  for (int i = threadIdx.x; i < NBK; i += 256) {
    hbase[i] = hcnt[i] ? atomicAdd(&bcur[i], hcnt[i]) : 0;
    hcnt[i] = 0;
  }
  __syncthreads();
  #pragma unroll
  for (int k = 0; k < BSE / 256; k++) {
    if (bk[k] >= 0) {
      int idx = atomicAdd(&hcnt[bk[k]], 1);
      recs[hbase[bk[k]] + idx] = rec[k];
    }
  }
}

// K4: merged hist + scan + off3/dinv/cntR + place. Bucket b's CSR base == bbase[b].
__global__ __launch_bounds__(256) void bucket_histplace(
    const unsigned* __restrict__ recs, const int* __restrict__ bbase,
    int* __restrict__ cntR, int* __restrict__ off3, float* __restrict__ dinv,
    unsigned short* __restrict__ sorted)
{
  __shared__ int h[768];
  __shared__ int cur[768];
  __shared__ int ts[256];
  int b = blockIdx.x;
  int t = threadIdx.x;
  for (int i = t; i < 768; i += 256) h[i] = 0;
  __syncthreads();
  int lo = bbase[b], hi = bbase[b + 1];
  for (int i = lo + t; i < hi; i += 256) {
    unsigned rec = recs[i];
    atomicAdd(&h[((rec >> 16) & 255) * 3 + ((rec >> 24) & 3)], 1);
  }
  __syncthreads();
  int s0 = h[3 * t], s1 = h[3 * t + 1], s2 = h[3 * t + 2];
  int tot = s0 + s1 + s2;
  ts[t] = tot;
  __syncthreads();
  for (int s = 1; s < 256; s <<= 1) {
    int v = (t >= s) ? ts[t - s] : 0;
    __syncthreads();
    ts[t] += v;
    __syncthreads();
  }
  int base = lo + ts[t] - tot;   // exclusive within bucket + bucket CSR base
  int n = b * 256 + t;
  if (n < NN) {
    off3[3 * n + 0] = base;
    off3[3 * n + 1] = base + s0;
    off3[3 * n + 2] = base + s0 + s1;
    cntR[3 * n + 0] = s0;
    cntR[3 * n + 1] = s1;
    cntR[3 * n + 2] = s2;
    dinv[3 * n + 0] = 1.0f / (float)(s0 > 1 ? s0 : 1);
    dinv[3 * n + 1] = 1.0f / (float)(s1 > 1 ? s1 : 1);
    dinv[3 * n + 2] = 1.0f / (float)(s2 > 1 ? s2 : 1);
  }
  cur[3 * t] = base; cur[3 * t + 1] = base + s0; cur[3 * t + 2] = base + s0 + s1;
  __syncthreads();
  for (int i = lo + t; i < hi; i += 256) {
    unsigned rec = recs[i];
    int idx = ((rec >> 16) & 255) * 3 + ((rec >> 24) & 3);
    int pos = atomicAdd(&cur[idx], 1);
    sorted[pos] = (unsigned short)(rec & 0xFFFF);
  }
}

// ---- fused: blocks 0-2 pack weights (fp16); blocks 3+ do layer-0 aggregation ----------------
__global__ __launch_bounds__(256) void agg0_pack(
    const float* __restrict__ x, const int* __restrict__ off3, const int* __restrict__ cntR,
    const unsigned short* __restrict__ sorted, float* __restrict__ agg0,
    const float* __restrict__ W1, const float* __restrict__ W2,
    const float* __restrict__ root1, const float* __restrict__ w1,
    const float* __restrict__ root2, const float* __restrict__ w2,
    unsigned short* __restrict__ pk3, unsigned short* __restrict__ pk2,
    unsigned short* __restrict__ pkl1, unsigned short* __restrict__ pkl2)
{
  if (blockIdx.x < 3) {
    if (blockIdx.x == 0) {
      for (int idx = threadIdx.x; idx < 8704; idx += 256) {
        int j = idx & 7, l = (idx >> 3) & 63, t = idx >> 9;
        int k = 16 * t + 8 * (l >> 5) + j;
        int n = l & 31;
        pk3[idx] = (k < 262) ? f2h(W1[k * 32 + n]) : (unsigned short)0;
      }
      for (int idx = threadIdx.x; idx < 512; idx += 256) {
        int j = idx & 7, l = idx >> 3;
        int k = (l >> 4) * 8 + j, n = l & 15;
        pk2[idx] = f2h(W2[k * 16 + n]);
      }
    } else {
      const float* root = (blockIdx.x == 1) ? root1 : root2;
      const float* W    = (blockIdx.x == 1) ? w1 : w2;
      unsigned short* pkL = (blockIdx.x == 1) ? pkl1 : pkl2;
      for (int idx = threadIdx.x; idx < 16384; idx += 256) {
        int j = idx & 7, l = (idx >> 3) & 63, nt = (idx >> 9) & 3, t = idx >> 11;
        int k = t * 32 + (l >> 4) * 8 + j;
        int n = nt * 16 + (l & 15);
        float w = (k < 64) ? root[k * 64 + n]
                           : W[((k - 64) >> 6) * 4096 + (k & 63) * 64 + n];
        pkL[idx] = f2h(w);
      }
    }
    return;
  }
  int wid = ((blockIdx.x - 3) * blockDim.x + threadIdx.x) >> 6;
  int lane = threadIdx.x & 63;
  int n = wid * 16 + (lane >> 2);
  int f = lane & 3;
  if (n >= NN) return;
  #pragma unroll
  for (int r = 0; r < 3; r++) {
    int st = off3[3 * n + r], len = cntR[3 * n + r];
    float a = 0.f;
    int i = 0;
    for (; i + 4 <= len; i += 4) {
      int s0 = sorted[st + i], s1 = sorted[st + i + 1];
      int s2 = sorted[st + i + 2], s3 = sorted[st + i + 3];
      float v0 = (f < 3) ? x[s0 * 3 + f] : 0.f;
      float v1 = (f < 3) ? x[s1 * 3 + f] : 0.f;
      float v2 = (f < 3) ? x[s2 * 3 + f] : 0.f;
      float v3 = (f < 3) ? x[s3 * 3 + f] : 0.f;
      a += (v0 + v1) + (v2 + v3);
    }
    for (; i < len; i++) {
      int s0 = sorted[st + i];
      a += (f < 3) ? x[s0 * 3 + f] : 0.f;
    }
    if (f < 3) agg0[n * 9 + r * 3 + f] = a;
  }
}

// ---------------- layer 0 node update (IN=3) + relu + residual + LN; fp16 hb out ------------
__global__ __launch_bounds__(256) void node0_kernel(
    const float* __restrict__ x, const float* __restrict__ agg0, const float* __restrict__ dinv,
    const float* __restrict__ w0, const float* __restrict__ root0, const float* __restrict__ b0,
    const float* __restrict__ res_w, const float* __restrict__ res_b,
    const float* __restrict__ g, const float* __restrict__ bb,
    unsigned short* __restrict__ hb)
{
  int wid = __builtin_amdgcn_readfirstlane((int)((blockIdx.x * blockDim.x + threadIdx.x) >> 6));
  int lane = threadIdx.x & 63;
  int n0 = wid * 8;
  if (n0 >= NN) return;
  float wr[3], ww[9], wres[3];
  #pragma unroll
  for (int i = 0; i < 3; i++) { wr[i] = root0[i * HD + lane]; wres[i] = res_w[i * HD + lane]; }
  #pragma unroll
  for (int i = 0; i < 9; i++) ww[i] = w0[i * HD + lane];
  float vb = b0[lane], vrb = res_b[lane], vg = g[lane], vbb = bb[lane];
  #pragma unroll
  for (int k = 0; k < 8; k++) {
    int nk = n0 + k;
    float xv[3];
    #pragma unroll
    for (int i = 0; i < 3; i++) xv[i] = x[nk * 3 + i];
    float v = vb;
    #pragma unroll
    for (int i = 0; i < 3; i++) v = fmaf(xv[i], wr[i], v);
    #pragma unroll
    for (int r = 0; r < 3; r++) {
      float s = 0.f;
      #pragma unroll
      for (int i = 0; i < 3; i++) s = fmaf(agg0[nk * 9 + r * 3 + i], ww[r * 3 + i], s);
      v = fmaf(dinv[nk * 3 + r], s, v);
    }
    v = fmaxf(v, 0.f);
    float res = vrb;
    #pragma unroll
    for (int i = 0; i < 3; i++) res = fmaf(xv[i], wres[i], res);
    float t = v + res;
    float mu = wave_sum(t) * 0.015625f;
    float dt = t - mu;
    float var = wave_sum(dt * dt) * 0.015625f;
    float o = dt * rsqrtf(var + 1e-5f) * vg + vbb;
    hb[(size_t)nk * HD + lane] = f2h(o);
  }
}

// ---- FUSED layer: CSR aggregation (packed-fp16, x8 unroll) -> LDS tile -> f16 MFMA --------
__global__ __launch_bounds__(256) void layer_fused(
    const unsigned short* __restrict__ hb_in, const unsigned short* __restrict__ pkL,
    const float* __restrict__ bias, const float* __restrict__ g, const float* __restrict__ bb,
    const int* __restrict__ off3, const int* __restrict__ cntR,
    const unsigned short* __restrict__ sorted, const float* __restrict__ dinv,
    unsigned short* __restrict__ hb_out)
{
  __shared__ unsigned short tile[4][16][256];   // 32 KiB / block
  int wv = threadIdx.x >> 6;
  int lane = threadIdx.x & 63;
  int wid = (blockIdx.x * blockDim.x + threadIdx.x) >> 6;
  int n0 = wid * 16;
  if (n0 >= NN) return;                          // NN%16==0; no block-wide barrier used
  char* T = (char*)&tile[wv][0][0];

  // ---- phase A: residual row + 3-relation aggregation, deep-MLP gather ----
  {
    int m = lane >> 2;        // node 0..15 within tile
    int q = lane & 3;         // 16-feature chunk
    int node = n0 + m;
    int swz = (m & 7) << 4;
    const unsigned short* hrow = hb_in + (size_t)node * HD + q * 16;
    uint4 rv0 = *(const uint4*)(hrow);
    uint4 rv1 = *(const uint4*)(hrow + 8);
    *(uint4*)(T + m * 512 + ((q * 32) ^ swz))      = rv0;
    *(uint4*)(T + m * 512 + ((q * 32 + 16) ^ swz)) = rv1;

    union U4 { uint4 u; hf2 h[4]; };
    #pragma unroll
    for (int r = 0; r < 3; r++) {
      int st = off3[node * 3 + r];
      int len = cntR[node * 3 + r];
      hf2 acc[8];
      #pragma unroll
      for (int j = 0; j < 8; j++) acc[j] = (hf2){(_Float16)0.f, (_Float16)0.f};
      int i = 0;
      for (; i + 8 <= len; i += 8) {
        int ss[8];
        #pragma unroll
        for (int j = 0; j < 8; j++) ss[j] = sorted[st + i + j];
        U4 lo[8], hiw[8];
        #pragma unroll
        for (int j = 0; j < 8; j++) {
          const uint4* p = (const uint4*)(hb_in + (size_t)ss[j] * HD + q * 16);
          lo[j].u = p[0]; hiw[j].u = p[1];
        }
        #pragma unroll
        for (int k = 0; k < 4; k++) {
          acc[k]     += ((lo[0].h[k] + lo[1].h[k]) + (lo[2].h[k] + lo[3].h[k]))
                      + ((lo[4].h[k] + lo[5].h[k]) + (lo[6].h[k] + lo[7].h[k]));
          acc[4 + k] += ((hiw[0].h[k] + hiw[1].h[k]) + (hiw[2].h[k] + hiw[3].h[k]))
                      + ((hiw[4].h[k] + hiw[5].h[k]) + (hiw[6].h[k] + hiw[7].h[k]));
        }
      }
      for (; i + 2 <= len; i += 2) {
        int s0 = sorted[st + i], s1 = sorted[st + i + 1];
        const uint4* p0 = (const uint4*)(hb_in + (size_t)s0 * HD + q * 16);
        const uint4* p1 = (const uint4*)(hb_in + (size_t)s1 * HD + q * 16);
        U4 a0, a1, b0, b1;
        a0.u = p0[0]; a1.u = p0[1]; b0.u = p1[0]; b1.u = p1[1];
        #pragma unroll
        for (int k = 0; k < 4; k++) {
          acc[k]     += a0.h[k] + b0.h[k];
          acc[4 + k] += a1.h[k] + b1.h[k];
        }
      }
      if (i < len) {
        int s0 = sorted[st + i];
        const uint4* p0 = (const uint4*)(hb_in + (size_t)s0 * HD + q * 16);
        U4 u0, u1;
        u0.u = p0[0]; u1.u = p0[1];
        #pragma unroll
        for (int k = 0; k < 4; k++) {
          acc[k]     += u0.h[k];
          acc[4 + k] += u1.h[k];
        }
      }
      float dv = dinv[node * 3 + r];
      unsigned pk[8];
      #pragma unroll
      for (int j = 0; j < 8; j++)
        pk[j] = f2h_pk((float)acc[j][0] * dv, (float)acc[j][1] * dv);
      uint4 w0 = make_uint4(pk[0], pk[1], pk[2], pk[3]);
      uint4 w1 = make_uint4(pk[4], pk[5], pk[6], pk[7]);
      *(uint4*)(T + m * 512 + ((128 + r * 128 + q * 32) ^ swz))      = w0;
      *(uint4*)(T + m * 512 + ((128 + r * 128 + q * 32 + 16) ^ swz)) = w1;
    }
  }

  // wave-local: drain ds_writes before ds_reads (same wave, different lanes)
  asm volatile("s_waitcnt lgkmcnt(0)" ::: "memory");
  __builtin_amdgcn_sched_barrier(0);

  // ---- phase B: node update as f16 MFMA GEMM (A from LDS), relu+residual+LN, write hb_out --
  int m2 = lane & 15, gq = lane >> 4;
  int swz2 = (m2 & 7) << 4;
  const half8* Bp = (const half8*)pkL;
  f32x4 acc[4];
  #pragma unroll
  for (int nt = 0; nt < 4; nt++) acc[nt] = (f32x4){0.f, 0.f, 0.f, 0.f};
  #pragma unroll
  for (int t = 0; t < 8; t++) {
    union AF { short8 s; half8 h; } af;
    af.s = *(const short8*)(T + m2 * 512 + ((gq * 16 + t * 64) ^ swz2));
    #pragma unroll
    for (int nt = 0; nt < 4; nt++)
      acc[nt] = __builtin_amdgcn_mfma_f32_16x16x32_f16(af.h, Bp[(t * 4 + nt) * 64 + lane], acc[nt], 0, 0, 0);
  }

  float bias_v[4], g_v[4], bb_v[4];
  #pragma unroll
  for (int nt = 0; nt < 4; nt++) {
    bias_v[nt] = bias[nt * 16 + m2];
    g_v[nt] = g[nt * 16 + m2];
    bb_v[nt] = bb[nt * 16 + m2];
  }
  #pragma unroll
  for (int rr = 0; rr < 4; rr++) {
    int lrow = gq * 4 + rr;              // C layout: row = quad*4 + reg
    int nodeo = n0 + lrow;
    int swzr = (lrow & 7) << 4;
    float tv[4], s = 0.f;
    #pragma unroll
    for (int nt = 0; nt < 4; nt++) {
      unsigned short rh = *(const unsigned short*)(T + lrow * 512 + (((nt * 16 + m2) * 2) ^ swzr));
      float res = h2f(rh);
      float v = fmaxf(acc[nt][rr] + bias_v[nt], 0.f) + res;
      tv[nt] = v; s += v;
    }
    #pragma unroll
    for (int o = 1; o < 16; o <<= 1) s += __shfl_xor(s, o, 64);
    float mu = s * 0.015625f;
    float s2 = 0.f;
    #pragma unroll
    for (int nt = 0; nt < 4; nt++) { float dd = tv[nt] - mu; s2 += dd * dd; }
    #pragma unroll
    for (int o = 1; o < 16; o <<= 1) s2 += __shfl_xor(s2, o, 64);
    float rstd = rsqrtf(s2 * 0.015625f + 1e-5f);
    #pragma unroll
    for (int nt = 0; nt < 4; nt++) {
      float o = (tv[nt] - mu) * rstd * g_v[nt] + bb_v[nt];
      hb_out[(size_t)nodeo * HD + nt * 16 + m2] = f2h(o);
    }
  }
}

// ------ decoder: pipelined, DT tiles of 32 edges/wave; weights in LDS; Z in fp16 ------------
__global__ __launch_bounds__(256, 5) void decoder_mfma(
    const unsigned short* __restrict__ hb, const int* __restrict__ ei, const float* __restrict__ ea,
    const unsigned short* __restrict__ pk3, const unsigned short* __restrict__ pk2,
    const float* __restrict__ B1, const float* __restrict__ B2,
    const float* __restrict__ W3, const float* __restrict__ B3,
    float* __restrict__ out)
{
  __shared__ unsigned short Zl16[4 * 32 * 34];   // 8704 B (fp16 Z, stride 34)
  __shared__ unsigned short Bsh[8704 + 512];     // pk3 + pk2 staged in LDS (18432 B)
  {
    unsigned* dsh = (unsigned*)Bsh;
    const unsigned* sp3 = (const unsigned*)pk3;
    for (int i = threadIdx.x; i < 4352; i += 256) dsh[i] = sp3[i];
    const unsigned* sp2 = (const unsigned*)pk2;
    if (threadIdx.x < 256) dsh[4352 + threadIdx.x] = sp2[threadIdx.x];
  }
  __syncthreads();

  int wv = threadIdx.x >> 6;
  int lane = threadIdx.x & 63;
  int r = lane & 31, u = lane >> 5;
  int base = (blockIdx.x * 4 + wv) * 32 * DT;

  int m = lane & 15, g = lane >> 4;
  float b1v = B1[r];
  float bias2 = B2[m];
  float w3v = W3[m];
  float b3v = B3[0];
  unsigned short* Z16 = Zl16 + wv * 1088;
  const half8* Bp  = (const half8*)Bsh;
  const half8* Bp2 = (const half8*)(Bsh + 8704);

  union u8h { short8 s8; half8 h8; hf2 h[4]; unsigned w[4]; };

  u8h hsA[4], hdA[4], hsB[4], hdB[4];
  float2 E0[3], E1[3], E2[3];

  auto GATH = [&](u8h* Hs, u8h* Hd, int s, int d) {
    const unsigned short* ps = hb + (size_t)s * HD + u * 8;
    const unsigned short* pq = hb + (size_t)d * HD + u * 8;
    #pragma unroll
    for (int t = 0; t < 4; t++) {
      Hs[t].s8 = *(const short8*)(ps + t * 16);
      Hd[t].s8 = *(const short8*)(pq + t * 16);
    }
  };
  auto LDEA = [&](float2* E, int e0t) {
    if (u == 0) {
      const float* er = ea + (size_t)(e0t + r) * 6;
      E[0] = *(const float2*)(er);
      E[1] = *(const float2*)(er + 2);
      E[2] = *(const float2*)(er + 4);
    }
  };
  auto COMP = [&](u8h* Hs, u8h* Hd, float2* E, int e0t) {
    u8h ad[4], pd[4];
    #pragma unroll
    for (int t = 0; t < 4; t++) {
      #pragma unroll
      for (int k = 0; k < 4; k++) {
        union { hf2 h; unsigned u; } dd;
        dd.h = Hs[t].h[k] - Hd[t].h[k];          // v_pk_add_f16 (neg)
        ad[t].w[k] = dd.u & 0x7FFF7FFFu;         // packed abs
        pd[t].h[k] = Hs[t].h[k] * Hd[t].h[k];    // v_pk_mul_f16
      }
    }
    u8h aea;
    aea.w[0] = 0; aea.w[1] = 0; aea.w[2] = 0; aea.w[3] = 0;
    if (u == 0) {
      aea.w[0] = f2h_pk(E[0].x, E[0].y);
      aea.w[1] = f2h_pk(E[1].x, E[1].y);
      aea.w[2] = f2h_pk(E[2].x, E[2].y);
    }

    f32x16 acc = {0.f, 0.f, 0.f, 0.f, 0.f, 0.f, 0.f, 0.f,
                  0.f, 0.f, 0.f, 0.f, 0.f, 0.f, 0.f, 0.f};
    #pragma unroll
    for (int t = 0; t < 4; t++)
      acc = __builtin_amdgcn_mfma_f32_32x32x16_f16(Hs[t].h8, Bp[t * 64 + lane], acc, 0, 0, 0);
    #pragma unroll
    for (int t = 0; t < 4; t++)
      acc = __builtin_amdgcn_mfma_f32_32x32x16_f16(Hd[t].h8, Bp[(4 + t) * 64 + lane], acc, 0, 0, 0);
    #pragma unroll
    for (int t = 0; t < 4; t++)
      acc = __builtin_amdgcn_mfma_f32_32x32x16_f16(ad[t].h8, Bp[(8 + t) * 64 + lane], acc, 0, 0, 0);
    #pragma unroll
    for (int t = 0; t < 4; t++)
      acc = __builtin_amdgcn_mfma_f32_32x32x16_f16(pd[t].h8, Bp[(12 + t) * 64 + lane], acc, 0, 0, 0);
    acc = __builtin_amdgcn_mfma_f32_32x32x16_f16(aea.h8, Bp[16 * 64 + lane], acc, 0, 0, 0);

    // Z write: fp16 packed pairs; acc[4k+j] -> feat 8k+4u+j (j=0..3 contiguous)
    #pragma unroll
    for (int k = 0; k < 4; k++) {
      unsigned w0 = f2h_pk(fmaxf(acc[4 * k + 0] + b1v, 0.f), fmaxf(acc[4 * k + 1] + b1v, 0.f));
      unsigned w1 = f2h_pk(fmaxf(acc[4 * k + 2] + b1v, 0.f), fmaxf(acc[4 * k + 3] + b1v, 0.f));
      *(unsigned*)(Z16 + r * 34 + 8 * k + 4 * u)     = w0;
      *(unsigned*)(Z16 + r * 34 + 8 * k + 4 * u + 2) = w1;
    }
    asm volatile("s_waitcnt lgkmcnt(0)" ::: "memory");
    __builtin_amdgcn_sched_barrier(0);

    #pragma unroll
    for (int q = 0; q < 2; q++) {
      u8h A2;
      #pragma unroll
      for (int j2 = 0; j2 < 4; j2++) {
        int e0 = g * 8 + 2 * j2, cc = q * 16 + m;
        unsigned lo = Z16[e0 * 34 + cc];
        unsigned hi = Z16[(e0 + 1) * 34 + cc];
        A2.w[j2] = lo | (hi << 16);
      }
      f32x4 acc2 = {0.f, 0.f, 0.f, 0.f};
      acc2 = __builtin_amdgcn_mfma_f32_16x16x32_f16(A2.h8, Bp2[lane], acc2, 0, 0, 0);

      float t0 = fmaxf(acc2[0] + bias2, 0.f) * w3v;
      float t1 = fmaxf(acc2[1] + bias2, 0.f) * w3v;
      float t2 = fmaxf(acc2[2] + bias2, 0.f) * w3v;
      float t3 = fmaxf(acc2[3] + bias2, 0.f) * w3v;
      #pragma unroll
      for (int off = 1; off < 16; off <<= 1) {
        t0 += __shfl_xor(t0, off, 64);
        t1 += __shfl_xor(t1, off, 64);
        t2 += __shfl_xor(t2, off, 64);
        t3 += __shfl_xor(t3, off, 64);
      }
      if (m < 4) {
        float val = (m == 0) ? t0 : (m == 1) ? t1 : (m == 2) ? t2 : t3;
        out[e0t + q * 16 + g * 4 + m] = val + b3v;
      }
    }
  };

  // ---- pipeline prologue: tile0 gathers + tile1 ids/ea in flight ----
  int s1, d1;
  {
    int s0 = ei[base + r], d0 = ei[NE + base + r];
    LDEA(E0, base);
    GATH(hsA, hdA, s0, d0);
  }
  s1 = ei[base + 32 + r]; d1 = ei[NE + base + 32 + r];
  LDEA(E1, base + 32);

  #pragma unroll
  for (int t = 0; t < DT; t++) {
    if (t + 1 < DT) GATH(hsB, hdB, s1, d1);       // issue next-tile gathers first
    int s2 = 0, d2 = 0;
    if (t + 2 < DT) {
      s2 = ei[base + (t + 2) * 32 + r]; d2 = ei[NE + base + (t + 2) * 32 + r];
      LDEA(E2, base + (t + 2) * 32);
    }
    COMP(hsA, hdA, E0, base + t * 32);            // compute phase: LDS/MFMA only
    #pragma unroll
    for (int k = 0; k < 4; k++) { hsA[k] = hsB[k]; hdA[k] = hdB[k]; }
    E0[0] = E1[0]; E0[1] = E1[1]; E0[2] = E1[2];
    E1[0] = E2[0]; E1[1] = E2[1]; E1[2] = E2[2];
    s1 = s2; d1 = d2;
  }
}

extern "C" void kernel_launch(void* const* d_in, const int* in_sizes, int n_in,
                              void* d_out, int out_size, void* d_ws, size_t ws_size,
                              hipStream_t stream) {
  const float* x      = (const float*)d_in[0];
  const int*   ei     = (const int*)d_in[1];
  const float* ea     = (const float*)d_in[2];
  const float* w0     = (const float*)d_in[3];
  const float* root0  = (const float*)d_in[4];
  const float* b0     = (const float*)d_in[5];
  const float* w1     = (const float*)d_in[6];
  const float* root1  = (const float*)d_in[7];
  const float* b1     = (const float*)d_in[8];
  const float* w2     = (const float*)d_in[9];
  const float* root2  = (const float*)d_in[10];
  const float* b2     = (const float*)d_in[11];
  const float* ln_g0  = (const float*)d_in[12];
  const float* ln_b0  = (const float*)d_in[13];
  const float* ln_g1  = (const float*)d_in[14];
  const float* ln_b1  = (const float*)d_in[15];
  const float* ln_g2  = (const float*)d_in[16];
  const float* ln_b2  = (const float*)d_in[17];
  const float* res_w  = (const float*)d_in[18];
  const float* res_b  = (const float*)d_in[19];
  const float* dec_w1 = (const float*)d_in[20];
  const float* dec_b1 = (const float*)d_in[21];
  const float* dec_w2 = (const float*)d_in[22];
  const float* dec_b2 = (const float*)d_in[23];
  const float* dec_w3 = (const float*)d_in[24];
  const float* dec_b3 = (const float*)d_in[25];

  char* ws = (char*)d_ws;
  unsigned* recs = (unsigned*)(ws + 0);                //  3,200,000 B
  int*   bcnt    = (int*)(ws + 3200000);               //      1,024 B (memset 0)
  int*   bbase   = (int*)(ws + 3201024);               //      1,024 B (197 ints)
  int*   bcur    = (int*)(ws + 3202048);               //      1,024 B
  float* agg0    = (float*)(ws + 3203072);             //  1,800,000 B
  int*   off3    = (int*)(ws + 5004096);               //    600,000 B
  float* dinv    = (float*)(ws + 5604096);             //    600,000 B
  int*   cntR    = (int*)(ws + 6204096);               //    600,000 B
  unsigned short* sorted = (unsigned short*)(ws + 6804096); // 1,600,000 B
  unsigned short* pk3  = (unsigned short*)(ws + 8404096);   //     17,408 B
  unsigned short* pkw2 = (unsigned short*)(ws + 8421504);   //      1,024 B
  unsigned short* pkl1 = (unsigned short*)(ws + 8422528);   //     32,768 B
  unsigned short* pkl2 = (unsigned short*)(ws + 8455296);   //     32,768 B
  unsigned short* hb   = (unsigned short*)(ws + 8488064);   //  6,400,000 B
  unsigned short* hb2  = (unsigned short*)(ws + 14888064);  //  6,400,000 B (end 21,288,064)

  hipMemsetAsync(bcnt, 0, 1024, stream);

  const int sort_blocks = (NE + BSE - 1) / BSE;       // 391

  bucket_count<<<sort_blocks, 256, 0, stream>>>(ei, bcnt);
  bucket_scan<<<1, 256, 0, stream>>>(bcnt, bbase, bcur);
  bucket_scatter<<<sort_blocks, 256, 0, stream>>>(ei, ea, bcur, recs);
  bucket_histplace<<<NBK, 256, 0, stream>>>(recs, bbase, cntR, off3, dinv, sorted);

  agg0_pack<<<3 + (NN + 63) / 64, 256, 0, stream>>>(x, off3, cntR, sorted, agg0,
                                                    dec_w1, dec_w2, root1, w1, root2, w2,
                                                    pk3, pkw2, pkl1, pkl2);

  const int node0_blocks = (NN / 8 + 3) / 4;          // 8 nodes/wave
  const int fused_blocks = (NN / 16 + 3) / 4;         // 16 nodes/wave, 4 waves/block

  node0_kernel<<<node0_blocks, 256, 0, stream>>>(x, agg0, dinv, w0, root0, b0,
                                                 res_w, res_b, ln_g0, ln_b0, hb);

  layer_fused<<<fused_blocks, 256, 0, stream>>>(hb, pkl1, b1, ln_g1, ln_b1,
                                                off3, cntR, sorted, dinv, hb2);
  layer_fused<<<fused_blocks, 256, 0, stream>>>(hb2, pkl2, b2, ln_g2, ln_b2,
                                                off3, cntR, sorted, dinv, hb);

  decoder_mfma<<<NE / (128 * DT), 256, 0, stream>>>(hb, ei, ea, pk3, pkw2, dec_b1,
                                                    dec_b2, dec_w3, dec_b3, (float*)d_out);
}

// Round 6
// 263.936 us; speedup vs baseline: 1.2187x; 1.2187x over previous
//
#include <hip/hip_runtime.h>
#include <math.h>

#define NN 50000
#define NE 800000
#define HD 64
#define NBK 196  // dst buckets (256 nodes each)
#define BSE 2048 // edges per block in bucket count/scatter
#define DT 5     // decoder tiles per wave (NE = 1250 blocks * 4 waves * 32 * DT)

typedef float f32x4 __attribute__((ext_vector_type(4)));
typedef float f32x16 __attribute__((ext_vector_type(16)));
typedef short short8 __attribute__((ext_vector_type(8)));
typedef _Float16 hf2 __attribute__((ext_vector_type(2)));
typedef _Float16 half8 __attribute__((ext_vector_type(8)));

__device__ __forceinline__ float wave_sum(float v) {
  #pragma unroll
  for (int off = 32; off > 0; off >>= 1) v += __shfl_xor(v, off, 64);
  return v;
}

// ---- fp16 conversion helpers ----
__device__ __forceinline__ unsigned f2h_pk(float a, float b) {
  auto v = __builtin_amdgcn_cvt_pkrtz(a, b);     // v_cvt_pkrtz_f16_f32
  union { decltype(v) h; unsigned u; } cv; cv.h = v; return cv.u;
}
__device__ __forceinline__ unsigned short f2h(float a) {
  union { _Float16 h; unsigned short u; } cv; cv.h = (_Float16)a; return cv.u;  // RNE
}
__device__ __forceinline__ float h2f(unsigned short b) {
  union { unsigned short u; _Float16 h; } v; v.u = b; return (float)v.h;
}

// =================== bucketed counting sort of edges by (dst, r) ===================
// K1: per-bucket edge counts (LDS histogram, 1 global atomic per bucket per block)
__global__ __launch_bounds__(256) void bucket_count(
    const int* __restrict__ ei, int* __restrict__ bcnt)
{
  __shared__ int h[NBK];
  for (int i = threadIdx.x; i < NBK; i += 256) h[i] = 0;
  __syncthreads();
  int e0 = blockIdx.x * BSE;
  #pragma unroll
  for (int k = 0; k < BSE / 256; k++) {
    int e = e0 + k * 256 + threadIdx.x;
    if (e < NE) atomicAdd(&h[ei[NE + e] >> 8], 1);
  }
  __syncthreads();
  for (int i = threadIdx.x; i < NBK; i += 256)
    if (h[i]) atomicAdd(&bcnt[i], h[i]);
}

// K2: exclusive scan of bucket counts -> bbase (197 entries), init bcur
__global__ __launch_bounds__(256) void bucket_scan(
    const int* __restrict__ bcnt, int* __restrict__ bbase, int* __restrict__ bcur)
{
  __shared__ int sd[256];
  int v = (threadIdx.x < NBK) ? bcnt[threadIdx.x] : 0;
  sd[threadIdx.x] = v;
  __syncthreads();
  for (int s = 1; s < 256; s <<= 1) {
    int t = (threadIdx.x >= s) ? sd[threadIdx.x - s] : 0;
    __syncthreads();
    sd[threadIdx.x] += t;
    __syncthreads();
  }
  if (threadIdx.x < NBK) {
    int ex = sd[threadIdx.x] - v;
    bbase[threadIdx.x] = ex;
    bcur[threadIdx.x] = ex;
  }
  if (threadIdx.x == 0) bbase[NBK] = NE;
}

// K3: scatter packed records (src | dlow<<16 | r<<24) into bucket-contiguous regions
__global__ __launch_bounds__(256) void bucket_scatter(
    const int* __restrict__ ei, const float* __restrict__ ea,
    int* __restrict__ bcur, unsigned* __restrict__ recs)
{
  __shared__ int hcnt[NBK], hbase[NBK];
  for (int i = threadIdx.x; i < NBK; i += 256) hcnt[i] = 0;
  __syncthreads();
  const float q1 = log1pf(5000.0f);
  const float q2 = log1pf(10000.0f);
  int e0 = blockIdx.x * BSE;
  unsigned rec[BSE / 256];
  int bk[BSE / 256];
  #pragma unroll
  for (int k = 0; k < BSE / 256; k++) {
    int e = e0 + k * 256 + threadIdx.x;
    bk[k] = -1;
    if (e < NE) {
      int s = ei[e], d = ei[NE + e];
      float dist = ea[(size_t)e * 6];
      int r = (dist > q1 ? 1 : 0) + (dist > q2 ? 1 : 0);
      rec[k] = (unsigned)s | ((unsigned)(d & 255) << 16) | ((unsigned)r << 24);
      bk[k] = d >> 8;
      atomicAdd(&hcnt[bk[k]], 1);
    }
  }
  __syncthreads();
  for (int i = threadIdx.x; i < NBK; i += 256) {
    hbase[i] = hcnt[i] ? atomicAdd(&bcur[i], hcnt[i]) : 0;
    hcnt[i] = 0;
  }
  __syncthreads();
  #pragma unroll
  for (int k = 0; k < BSE / 256; k++) {
    if (bk[k] >= 0) {
      int idx = atomicAdd(&hcnt[bk[k]], 1);
      recs[hbase[bk[k]] + idx] = rec[k];
    }
  }
}

// K4: merged hist + scan + off3/dinv/cntR + place. Bucket b's CSR base == bbase[b].
__global__ __launch_bounds__(256) void bucket_histplace(
    const unsigned* __restrict__ recs, const int* __restrict__ bbase,
    int* __restrict__ cntR, int* __restrict__ off3, float* __restrict__ dinv,
    unsigned short* __restrict__ sorted)
{
  __shared__ int h[768];
  __shared__ int cur[768];
  __shared__ int ts[256];
  int b = blockIdx.x;
  int t = threadIdx.x;
  for (int i = t; i < 768; i += 256) h[i] = 0;
  __syncthreads();
  int lo = bbase[b], hi = bbase[b + 1];
  for (int i = lo + t; i < hi; i += 256) {
    unsigned rec = recs[i];
    atomicAdd(&h[((rec >> 16) & 255) * 3 + ((rec >> 24) & 3)], 1);
  }
  __syncthreads();
  int s0 = h[3 * t], s1 = h[3 * t + 1], s2 = h[3 * t + 2];
  int tot = s0 + s1 + s2;
  ts[t] = tot;
  __syncthreads();
  for (int s = 1; s < 256; s <<= 1) {
    int v = (t >= s) ? ts[t - s] : 0;
    __syncthreads();
    ts[t] += v;
    __syncthreads();
  }
  int base = lo + ts[t] - tot;   // exclusive within bucket + bucket CSR base
  int n = b * 256 + t;
  if (n < NN) {
    off3[3 * n + 0] = base;
    off3[3 * n + 1] = base + s0;
    off3[3 * n + 2] = base + s0 + s1;
    cntR[3 * n + 0] = s0;
    cntR[3 * n + 1] = s1;
    cntR[3 * n + 2] = s2;
    dinv[3 * n + 0] = 1.0f / (float)(s0 > 1 ? s0 : 1);
    dinv[3 * n + 1] = 1.0f / (float)(s1 > 1 ? s1 : 1);
    dinv[3 * n + 2] = 1.0f / (float)(s2 > 1 ? s2 : 1);
  }
  cur[3 * t] = base; cur[3 * t + 1] = base + s0; cur[3 * t + 2] = base + s0 + s1;
  __syncthreads();
  for (int i = lo + t; i < hi; i += 256) {
    unsigned rec = recs[i];
    int idx = ((rec >> 16) & 255) * 3 + ((rec >> 24) & 3);
    int pos = atomicAdd(&cur[idx], 1);
    sorted[pos] = (unsigned short)(rec & 0xFFFF);
  }
}

// ---- fused: blocks 0-2 pack weights (fp16); blocks 3+ do layer-0 aggregation ----------------
__global__ __launch_bounds__(256) void agg0_pack(
    const float* __restrict__ x, const int* __restrict__ off3, const int* __restrict__ cntR,
    const unsigned short* __restrict__ sorted, float* __restrict__ agg0,
    const float* __restrict__ W1, const float* __restrict__ W2,
    const float* __restrict__ root1, const float* __restrict__ w1,
    const float* __restrict__ root2, const float* __restrict__ w2,
    unsigned short* __restrict__ pk3, unsigned short* __restrict__ pk2,
    unsigned short* __restrict__ pkl1, unsigned short* __restrict__ pkl2)
{
  if (blockIdx.x < 3) {
    if (blockIdx.x == 0) {
      for (int idx = threadIdx.x; idx < 8704; idx += 256) {
        int j = idx & 7, l = (idx >> 3) & 63, t = idx >> 9;
        int k = 16 * t + 8 * (l >> 5) + j;
        int n = l & 31;
        pk3[idx] = (k < 262) ? f2h(W1[k * 32 + n]) : (unsigned short)0;
      }
      for (int idx = threadIdx.x; idx < 512; idx += 256) {
        int j = idx & 7, l = idx >> 3;
        int k = (l >> 4) * 8 + j, n = l & 15;
        pk2[idx] = f2h(W2[k * 16 + n]);
      }
    } else {
      const float* root = (blockIdx.x == 1) ? root1 : root2;
      const float* W    = (blockIdx.x == 1) ? w1 : w2;
      unsigned short* pkL = (blockIdx.x == 1) ? pkl1 : pkl2;
      for (int idx = threadIdx.x; idx < 16384; idx += 256) {
        int j = idx & 7, l = (idx >> 3) & 63, nt = (idx >> 9) & 3, t = idx >> 11;
        int k = t * 32 + (l >> 4) * 8 + j;
        int n = nt * 16 + (l & 15);
        float w = (k < 64) ? root[k * 64 + n]
                           : W[((k - 64) >> 6) * 4096 + (k & 63) * 64 + n];
        pkL[idx] = f2h(w);
      }
    }
    return;
  }
  int wid = ((blockIdx.x - 3) * blockDim.x + threadIdx.x) >> 6;
  int lane = threadIdx.x & 63;
  int n = wid * 16 + (lane >> 2);
  int f = lane & 3;
  if (n >= NN) return;
  #pragma unroll
  for (int r = 0; r < 3; r++) {
    int st = off3[3 * n + r], len = cntR[3 * n + r];
    float a = 0.f;
    int i = 0;
    for (; i + 4 <= len; i += 4) {
      int s0 = sorted[st + i], s1 = sorted[st + i + 1];
      int s2 = sorted[st + i + 2], s3 = sorted[st + i + 3];
      float v0 = (f < 3) ? x[s0 * 3 + f] : 0.f;
      float v1 = (f < 3) ? x[s1 * 3 + f] : 0.f;
      float v2 = (f < 3) ? x[s2 * 3 + f] : 0.f;
      float v3 = (f < 3) ? x[s3 * 3 + f] : 0.f;
      a += (v0 + v1) + (v2 + v3);
    }
    for (; i < len; i++) {
      int s0 = sorted[st + i];
      a += (f < 3) ? x[s0 * 3 + f] : 0.f;
    }
    if (f < 3) agg0[n * 9 + r * 3 + f] = a;
  }
}

// ---------------- layer 0 node update (IN=3) + relu + residual + LN; fp16 hb out ------------
__global__ __launch_bounds__(256) void node0_kernel(
    const float* __restrict__ x, const float* __restrict__ agg0, const float* __restrict__ dinv,
    const float* __restrict__ w0, const float* __restrict__ root0, const float* __restrict__ b0,
    const float* __restrict__ res_w, const float* __restrict__ res_b,
    const float* __restrict__ g, const float* __restrict__ bb,
    unsigned short* __restrict__ hb)
{
  int wid = __builtin_amdgcn_readfirstlane((int)((blockIdx.x * blockDim.x + threadIdx.x) >> 6));
  int lane = threadIdx.x & 63;
  int n0 = wid * 8;
  if (n0 >= NN) return;
  float wr[3], ww[9], wres[3];
  #pragma unroll
  for (int i = 0; i < 3; i++) { wr[i] = root0[i * HD + lane]; wres[i] = res_w[i * HD + lane]; }
  #pragma unroll
  for (int i = 0; i < 9; i++) ww[i] = w0[i * HD + lane];
  float vb = b0[lane], vrb = res_b[lane], vg = g[lane], vbb = bb[lane];
  #pragma unroll
  for (int k = 0; k < 8; k++) {
    int nk = n0 + k;
    float xv[3];
    #pragma unroll
    for (int i = 0; i < 3; i++) xv[i] = x[nk * 3 + i];
    float v = vb;
    #pragma unroll
    for (int i = 0; i < 3; i++) v = fmaf(xv[i], wr[i], v);
    #pragma unroll
    for (int r = 0; r < 3; r++) {
      float s = 0.f;
      #pragma unroll
      for (int i = 0; i < 3; i++) s = fmaf(agg0[nk * 9 + r * 3 + i], ww[r * 3 + i], s);
      v = fmaf(dinv[nk * 3 + r], s, v);
    }
    v = fmaxf(v, 0.f);
    float res = vrb;
    #pragma unroll
    for (int i = 0; i < 3; i++) res = fmaf(xv[i], wres[i], res);
    float t = v + res;
    float mu = wave_sum(t) * 0.015625f;
    float dt = t - mu;
    float var = wave_sum(dt * dt) * 0.015625f;
    float o = dt * rsqrtf(var + 1e-5f) * vg + vbb;
    hb[(size_t)nk * HD + lane] = f2h(o);
  }
}

// ---- FUSED layer: CSR aggregation (packed-fp16, x8 unroll) -> LDS tile -> f16 MFMA --------
__global__ __launch_bounds__(256) void layer_fused(
    const unsigned short* __restrict__ hb_in, const unsigned short* __restrict__ pkL,
    const float* __restrict__ bias, const float* __restrict__ g, const float* __restrict__ bb,
    const int* __restrict__ off3, const int* __restrict__ cntR,
    const unsigned short* __restrict__ sorted, const float* __restrict__ dinv,
    unsigned short* __restrict__ hb_out)
{
  __shared__ unsigned short tile[4][16][256];   // 32 KiB / block
  int wv = threadIdx.x >> 6;
  int lane = threadIdx.x & 63;
  int wid = (blockIdx.x * blockDim.x + threadIdx.x) >> 6;
  int n0 = wid * 16;
  if (n0 >= NN) return;                          // NN%16==0; no block-wide barrier used
  char* T = (char*)&tile[wv][0][0];

  // ---- phase A: residual row + 3-relation aggregation, deep-MLP gather ----
  {
    int m = lane >> 2;        // node 0..15 within tile
    int q = lane & 3;         // 16-feature chunk
    int node = n0 + m;
    int swz = (m & 7) << 4;
    const unsigned short* hrow = hb_in + (size_t)node * HD + q * 16;
    uint4 rv0 = *(const uint4*)(hrow);
    uint4 rv1 = *(const uint4*)(hrow + 8);
    *(uint4*)(T + m * 512 + ((q * 32) ^ swz))      = rv0;
    *(uint4*)(T + m * 512 + ((q * 32 + 16) ^ swz)) = rv1;

    union U4 { uint4 u; hf2 h[4]; };
    #pragma unroll
    for (int r = 0; r < 3; r++) {
      int st = off3[node * 3 + r];
      int len = cntR[node * 3 + r];
      hf2 acc[8];
      #pragma unroll
      for (int j = 0; j < 8; j++) acc[j] = (hf2){(_Float16)0.f, (_Float16)0.f};
      int i = 0;
      for (; i + 8 <= len; i += 8) {
        int ss[8];
        #pragma unroll
        for (int j = 0; j < 8; j++) ss[j] = sorted[st + i + j];
        U4 lo[8], hiw[8];
        #pragma unroll
        for (int j = 0; j < 8; j++) {
          const uint4* p = (const uint4*)(hb_in + (size_t)ss[j] * HD + q * 16);
          lo[j].u = p[0]; hiw[j].u = p[1];
        }
        #pragma unroll
        for (int k = 0; k < 4; k++) {
          acc[k]     += ((lo[0].h[k] + lo[1].h[k]) + (lo[2].h[k] + lo[3].h[k]))
                      + ((lo[4].h[k] + lo[5].h[k]) + (lo[6].h[k] + lo[7].h[k]));
          acc[4 + k] += ((hiw[0].h[k] + hiw[1].h[k]) + (hiw[2].h[k] + hiw[3].h[k]))
                      + ((hiw[4].h[k] + hiw[5].h[k]) + (hiw[6].h[k] + hiw[7].h[k]));
        }
      }
      for (; i + 2 <= len; i += 2) {
        int s0 = sorted[st + i], s1 = sorted[st + i + 1];
        const uint4* p0 = (const uint4*)(hb_in + (size_t)s0 * HD + q * 16);
        const uint4* p1 = (const uint4*)(hb_in + (size_t)s1 * HD + q * 16);
        U4 a0, a1, b0, b1;
        a0.u = p0[0]; a1.u = p0[1]; b0.u = p1[0]; b1.u = p1[1];
        #pragma unroll
        for (int k = 0; k < 4; k++) {
          acc[k]     += a0.h[k] + b0.h[k];
          acc[4 + k] += a1.h[k] + b1.h[k];
        }
      }
      if (i < len) {
        int s0 = sorted[st + i];
        const uint4* p0 = (const uint4*)(hb_in + (size_t)s0 * HD + q * 16);
        U4 u0, u1;
        u0.u = p0[0]; u1.u = p0[1];
        #pragma unroll
        for (int k = 0; k < 4; k++) {
          acc[k]     += u0.h[k];
          acc[4 + k] += u1.h[k];
        }
      }
      float dv = dinv[node * 3 + r];
      unsigned pk[8];
      #pragma unroll
      for (int j = 0; j < 8; j++)
        pk[j] = f2h_pk((float)acc[j][0] * dv, (float)acc[j][1] * dv);
      uint4 w0 = make_uint4(pk[0], pk[1], pk[2], pk[3]);
      uint4 w1 = make_uint4(pk[4], pk[5], pk[6], pk[7]);
      *(uint4*)(T + m * 512 + ((128 + r * 128 + q * 32) ^ swz))      = w0;
      *(uint4*)(T + m * 512 + ((128 + r * 128 + q * 32 + 16) ^ swz)) = w1;
    }
  }

  // wave-local: drain ds_writes before ds_reads (same wave, different lanes)
  asm volatile("s_waitcnt lgkmcnt(0)" ::: "memory");
  __builtin_amdgcn_sched_barrier(0);

  // ---- phase B: node update as f16 MFMA GEMM (A from LDS), relu+residual+LN, write hb_out --
  int m2 = lane & 15, gq = lane >> 4;
  int swz2 = (m2 & 7) << 4;
  const half8* Bp = (const half8*)pkL;
  f32x4 acc[4];
  #pragma unroll
  for (int nt = 0; nt < 4; nt++) acc[nt] = (f32x4){0.f, 0.f, 0.f, 0.f};
  #pragma unroll
  for (int t = 0; t < 8; t++) {
    union AF { short8 s; half8 h; } af;
    af.s = *(const short8*)(T + m2 * 512 + ((gq * 16 + t * 64) ^ swz2));
    #pragma unroll
    for (int nt = 0; nt < 4; nt++)
      acc[nt] = __builtin_amdgcn_mfma_f32_16x16x32_f16(af.h, Bp[(t * 4 + nt) * 64 + lane], acc[nt], 0, 0, 0);
  }

  float bias_v[4], g_v[4], bb_v[4];
  #pragma unroll
  for (int nt = 0; nt < 4; nt++) {
    bias_v[nt] = bias[nt * 16 + m2];
    g_v[nt] = g[nt * 16 + m2];
    bb_v[nt] = bb[nt * 16 + m2];
  }
  #pragma unroll
  for (int rr = 0; rr < 4; rr++) {
    int lrow = gq * 4 + rr;              // C layout: row = quad*4 + reg
    int nodeo = n0 + lrow;
    int swzr = (lrow & 7) << 4;
    float tv[4], s = 0.f;
    #pragma unroll
    for (int nt = 0; nt < 4; nt++) {
      unsigned short rh = *(const unsigned short*)(T + lrow * 512 + (((nt * 16 + m2) * 2) ^ swzr));
      float res = h2f(rh);
      float v = fmaxf(acc[nt][rr] + bias_v[nt], 0.f) + res;
      tv[nt] = v; s += v;
    }
    #pragma unroll
    for (int o = 1; o < 16; o <<= 1) s += __shfl_xor(s, o, 64);
    float mu = s * 0.015625f;
    float s2 = 0.f;
    #pragma unroll
    for (int nt = 0; nt < 4; nt++) { float dd = tv[nt] - mu; s2 += dd * dd; }
    #pragma unroll
    for (int o = 1; o < 16; o <<= 1) s2 += __shfl_xor(s2, o, 64);
    float rstd = rsqrtf(s2 * 0.015625f + 1e-5f);
    #pragma unroll
    for (int nt = 0; nt < 4; nt++) {
      float o = (tv[nt] - mu) * rstd * g_v[nt] + bb_v[nt];
      hb_out[(size_t)nodeo * HD + nt * 16 + m2] = f2h(o);
    }
  }
}

// ------ decoder: pipelined, DT tiles of 32 edges/wave; weights in LDS; Z in fp16 ------------
// NOTE: no min-waves clamp — round 5's __launch_bounds__(256,5) spilled the pipeline
// state to scratch (WRITE_SIZE 3 MB -> 152 MB). LDS 27,136 B still allows 6 blocks/CU.
__global__ __launch_bounds__(256) void decoder_mfma(
    const unsigned short* __restrict__ hb, const int* __restrict__ ei, const float* __restrict__ ea,
    const unsigned short* __restrict__ pk3, const unsigned short* __restrict__ pk2,
    const float* __restrict__ B1, const float* __restrict__ B2,
    const float* __restrict__ W3, const float* __restrict__ B3,
    float* __restrict__ out)
{
  __shared__ unsigned short Zl16[4 * 32 * 34];   // 8704 B (fp16 Z, stride 34)
  __shared__ unsigned short Bsh[8704 + 512];     // pk3 + pk2 staged in LDS (18432 B)
  {
    unsigned* dsh = (unsigned*)Bsh;
    const unsigned* sp3 = (const unsigned*)pk3;
    for (int i = threadIdx.x; i < 4352; i += 256) dsh[i] = sp3[i];
    const unsigned* sp2 = (const unsigned*)pk2;
    if (threadIdx.x < 256) dsh[4352 + threadIdx.x] = sp2[threadIdx.x];
  }
  __syncthreads();

  int wv = threadIdx.x >> 6;
  int lane = threadIdx.x & 63;
  int r = lane & 31, u = lane >> 5;
  int base = (blockIdx.x * 4 + wv) * 32 * DT;

  int m = lane & 15, g = lane >> 4;
  float b1v = B1[r];
  float bias2 = B2[m];
  float w3v = W3[m];
  float b3v = B3[0];
  unsigned short* Z16 = Zl16 + wv * 1088;
  const half8* Bp  = (const half8*)Bsh;
  const half8* Bp2 = (const half8*)(Bsh + 8704);

  union u8h { short8 s8; half8 h8; hf2 h[4]; unsigned w[4]; };

  u8h hsA[4], hdA[4], hsB[4], hdB[4];
  float2 E0[3], E1[3], E2[3];

  auto GATH = [&](u8h* Hs, u8h* Hd, int s, int d) {
    const unsigned short* ps = hb + (size_t)s * HD + u * 8;
    const unsigned short* pq = hb + (size_t)d * HD + u * 8;
    #pragma unroll
    for (int t = 0; t < 4; t++) {
      Hs[t].s8 = *(const short8*)(ps + t * 16);
      Hd[t].s8 = *(const short8*)(pq + t * 16);
    }
  };
  auto LDEA = [&](float2* E, int e0t) {
    if (u == 0) {
      const float* er = ea + (size_t)(e0t + r) * 6;
      E[0] = *(const float2*)(er);
      E[1] = *(const float2*)(er + 2);
      E[2] = *(const float2*)(er + 4);
    }
  };
  auto COMP = [&](u8h* Hs, u8h* Hd, float2* E, int e0t) {
    u8h ad[4], pd[4];
    #pragma unroll
    for (int t = 0; t < 4; t++) {
      #pragma unroll
      for (int k = 0; k < 4; k++) {
        union { hf2 h; unsigned u; } dd;
        dd.h = Hs[t].h[k] - Hd[t].h[k];          // v_pk_add_f16 (neg)
        ad[t].w[k] = dd.u & 0x7FFF7FFFu;         // packed abs
        pd[t].h[k] = Hs[t].h[k] * Hd[t].h[k];    // v_pk_mul_f16
      }
    }
    u8h aea;
    aea.w[0] = 0; aea.w[1] = 0; aea.w[2] = 0; aea.w[3] = 0;
    if (u == 0) {
      aea.w[0] = f2h_pk(E[0].x, E[0].y);
      aea.w[1] = f2h_pk(E[1].x, E[1].y);
      aea.w[2] = f2h_pk(E[2].x, E[2].y);
    }

    f32x16 acc = {0.f, 0.f, 0.f, 0.f, 0.f, 0.f, 0.f, 0.f,
                  0.f, 0.f, 0.f, 0.f, 0.f, 0.f, 0.f, 0.f};
    #pragma unroll
    for (int t = 0; t < 4; t++)
      acc = __builtin_amdgcn_mfma_f32_32x32x16_f16(Hs[t].h8, Bp[t * 64 + lane], acc, 0, 0, 0);
    #pragma unroll
    for (int t = 0; t < 4; t++)
      acc = __builtin_amdgcn_mfma_f32_32x32x16_f16(Hd[t].h8, Bp[(4 + t) * 64 + lane], acc, 0, 0, 0);
    #pragma unroll
    for (int t = 0; t < 4; t++)
      acc = __builtin_amdgcn_mfma_f32_32x32x16_f16(ad[t].h8, Bp[(8 + t) * 64 + lane], acc, 0, 0, 0);
    #pragma unroll
    for (int t = 0; t < 4; t++)
      acc = __builtin_amdgcn_mfma_f32_32x32x16_f16(pd[t].h8, Bp[(12 + t) * 64 + lane], acc, 0, 0, 0);
    acc = __builtin_amdgcn_mfma_f32_32x32x16_f16(aea.h8, Bp[16 * 64 + lane], acc, 0, 0, 0);

    // Z write: fp16 packed pairs; acc[4k+j] -> feat 8k+4u+j (j=0..3 contiguous)
    #pragma unroll
    for (int k = 0; k < 4; k++) {
      unsigned w0 = f2h_pk(fmaxf(acc[4 * k + 0] + b1v, 0.f), fmaxf(acc[4 * k + 1] + b1v, 0.f));
      unsigned w1 = f2h_pk(fmaxf(acc[4 * k + 2] + b1v, 0.f), fmaxf(acc[4 * k + 3] + b1v, 0.f));
      *(unsigned*)(Z16 + r * 34 + 8 * k + 4 * u)     = w0;
      *(unsigned*)(Z16 + r * 34 + 8 * k + 4 * u + 2) = w1;
    }
    asm volatile("s_waitcnt lgkmcnt(0)" ::: "memory");
    __builtin_amdgcn_sched_barrier(0);

    #pragma unroll
    for (int q = 0; q < 2; q++) {
      u8h A2;
      #pragma unroll
      for (int j2 = 0; j2 < 4; j2++) {
        int e0 = g * 8 + 2 * j2, cc = q * 16 + m;
        unsigned lo = Z16[e0 * 34 + cc];
        unsigned hi = Z16[(e0 + 1) * 34 + cc];
        A2.w[j2] = lo | (hi << 16);
      }
      f32x4 acc2 = {0.f, 0.f, 0.f, 0.f};
      acc2 = __builtin_amdgcn_mfma_f32_16x16x32_f16(A2.h8, Bp2[lane], acc2, 0, 0, 0);

      float t0 = fmaxf(acc2[0] + bias2, 0.f) * w3v;
      float t1 = fmaxf(acc2[1] + bias2, 0.f) * w3v;
      float t2 = fmaxf(acc2[2] + bias2, 0.f) * w3v;
      float t3 = fmaxf(acc2[3] + bias2, 0.f) * w3v;
      #pragma unroll
      for (int off = 1; off < 16; off <<= 1) {
        t0 += __shfl_xor(t0, off, 64);
        t1 += __shfl_xor(t1, off, 64);
        t2 += __shfl_xor(t2, off, 64);
        t3 += __shfl_xor(t3, off, 64);
      }
      if (m < 4) {
        float val = (m == 0) ? t0 : (m == 1) ? t1 : (m == 2) ? t2 : t3;
        out[e0t + q * 16 + g * 4 + m] = val + b3v;
      }
    }
  };

  // ---- pipeline prologue: tile0 gathers + tile1 ids/ea in flight ----
  int s1, d1;
  {
    int s0 = ei[base + r], d0 = ei[NE + base + r];
    LDEA(E0, base);
    GATH(hsA, hdA, s0, d0);
  }
  s1 = ei[base + 32 + r]; d1 = ei[NE + base + 32 + r];
  LDEA(E1, base + 32);

  #pragma unroll
  for (int t = 0; t < DT; t++) {
    if (t + 1 < DT) GATH(hsB, hdB, s1, d1);       // issue next-tile gathers first
    int s2 = 0, d2 = 0;
    if (t + 2 < DT) {
      s2 = ei[base + (t + 2) * 32 + r]; d2 = ei[NE + base + (t + 2) * 32 + r];
      LDEA(E2, base + (t + 2) * 32);
    }
    COMP(hsA, hdA, E0, base + t * 32);            // compute phase: LDS/MFMA only
    #pragma unroll
    for (int k = 0; k < 4; k++) { hsA[k] = hsB[k]; hdA[k] = hdB[k]; }
    E0[0] = E1[0]; E0[1] = E1[1]; E0[2] = E1[2];
    E1[0] = E2[0]; E1[1] = E2[1]; E1[2] = E2[2];
    s1 = s2; d1 = d2;
  }
}

extern "C" void kernel_launch(void* const* d_in, const int* in_sizes, int n_in,
                              void* d_out, int out_size, void* d_ws, size_t ws_size,
                              hipStream_t stream) {
  const float* x      = (const float*)d_in[0];
  const int*   ei     = (const int*)d_in[1];
  const float* ea     = (const float*)d_in[2];
  const float* w0     = (const float*)d_in[3];
  const float* root0  = (const float*)d_in[4];
  const float* b0     = (const float*)d_in[5];
  const float* w1     = (const float*)d_in[6];
  const float* root1  = (const float*)d_in[7];
  const float* b1     = (const float*)d_in[8];
  const float* w2     = (const float*)d_in[9];
  const float* root2  = (const float*)d_in[10];
  const float* b2     = (const float*)d_in[11];
  const float* ln_g0  = (const float*)d_in[12];
  const float* ln_b0  = (const float*)d_in[13];
  const float* ln_g1  = (const float*)d_in[14];
  const float* ln_b1  = (const float*)d_in[15];
  const float* ln_g2  = (const float*)d_in[16];
  const float* ln_b2  = (const float*)d_in[17];
  const float* res_w  = (const float*)d_in[18];
  const float* res_b  = (const float*)d_in[19];
  const float* dec_w1 = (const float*)d_in[20];
  const float* dec_b1 = (const float*)d_in[21];
  const float* dec_w2 = (const float*)d_in[22];
  const float* dec_b2 = (const float*)d_in[23];
  const float* dec_w3 = (const float*)d_in[24];
  const float* dec_b3 = (const float*)d_in[25];

  char* ws = (char*)d_ws;
  unsigned* recs = (unsigned*)(ws + 0);                //  3,200,000 B
  int*   bcnt    = (int*)(ws + 3200000);               //      1,024 B (memset 0)
  int*   bbase   = (int*)(ws + 3201024);               //      1,024 B (197 ints)
  int*   bcur    = (int*)(ws + 3202048);               //      1,024 B
  float* agg0    = (float*)(ws + 3203072);             //  1,800,000 B
  int*   off3    = (int*)(ws + 5004096);               //    600,000 B
  float* dinv    = (float*)(ws + 5604096);             //    600,000 B
  int*   cntR    = (int*)(ws + 6204096);               //    600,000 B
  unsigned short* sorted = (unsigned short*)(ws + 6804096); // 1,600,000 B
  unsigned short* pk3  = (unsigned short*)(ws + 8404096);   //     17,408 B
  unsigned short* pkw2 = (unsigned short*)(ws + 8421504);   //      1,024 B
  unsigned short* pkl1 = (unsigned short*)(ws + 8422528);   //     32,768 B
  unsigned short* pkl2 = (unsigned short*)(ws + 8455296);   //     32,768 B
  unsigned short* hb   = (unsigned short*)(ws + 8488064);   //  6,400,000 B
  unsigned short* hb2  = (unsigned short*)(ws + 14888064);  //  6,400,000 B (end 21,288,064)

  hipMemsetAsync(bcnt, 0, 1024, stream);

  const int sort_blocks = (NE + BSE - 1) / BSE;       // 391

  bucket_count<<<sort_blocks, 256, 0, stream>>>(ei, bcnt);
  bucket_scan<<<1, 256, 0, stream>>>(bcnt, bbase, bcur);
  bucket_scatter<<<sort_blocks, 256, 0, stream>>>(ei, ea, bcur, recs);
  bucket_histplace<<<NBK, 256, 0, stream>>>(recs, bbase, cntR, off3, dinv, sorted);

  agg0_pack<<<3 + (NN + 63) / 64, 256, 0, stream>>>(x, off3, cntR, sorted, agg0,
                                                    dec_w1, dec_w2, root1, w1, root2, w2,
                                                    pk3, pkw2, pkl1, pkl2);

  const int node0_blocks = (NN / 8 + 3) / 4;          // 8 nodes/wave
  const int fused_blocks = (NN / 16 + 3) / 4;         // 16 nodes/wave, 4 waves/block

  node0_kernel<<<node0_blocks, 256, 0, stream>>>(x, agg0, dinv, w0, root0, b0,
                                                 res_w, res_b, ln_g0, ln_b0, hb);

  layer_fused<<<fused_blocks, 256, 0, stream>>>(hb, pkl1, b1, ln_g1, ln_b1,
                                                off3, cntR, sorted, dinv, hb2);
  layer_fused<<<fused_blocks, 256, 0, stream>>>(hb2, pkl2, b2, ln_g2, ln_b2,
                                                off3, cntR, sorted, dinv, hb);

  decoder_mfma<<<NE / (128 * DT), 256, 0, stream>>>(hb, ei, ea, pk3, pkw2, dec_b1,
                                                    dec_b2, dec_w3, dec_b3, (float*)d_out);
}